// Round 7
// baseline (6912.486 us; speedup 1.0000x reference)
//
#include <hip/hip_runtime.h>

#define DI __device__ __forceinline__

typedef __attribute__((ext_vector_type(4))) float  f32x4;
typedef __attribute__((ext_vector_type(8))) short  s16x8;
typedef __attribute__((ext_vector_type(8))) __bf16 bf16x8;

// ---------------- constants ----------------
constexpr int S_   = 256;
constexpr int B_   = 512;
constexpr int H_   = 512;
constexpr int KP_  = 320;   // padded 300
constexpr int ALD_ = 832;   // act row: [xt 0..320 | htm 320..832]
constexpr int NRING = 34;
constexpr int NWG  = 256;   // persistent workgroups (== CU count)
constexpr size_t HSLOT = 512 * 512;  // elements per hs slot

// ---------------- workspace layout (bytes) ----------------
constexpr size_t OFF_XIN = 0;                              // bf16 [S][B][320]
constexpr size_t SZ_XIN  = (size_t)S_ * B_ * KP_ * 2;
constexpr size_t OFF_U   = OFF_XIN + SZ_XIN;               // f32 [B][S][64]
constexpr size_t SZ_U    = (size_t)B_ * S_ * 64 * 4;
constexpr size_t OFF_HS  = OFF_U + SZ_U;                   // bf16 ring [34][512][512]
constexpr size_t SZ_HS   = (size_t)NRING * HSLOT * 2;
constexpr size_t OFF_ACT = OFF_HS + SZ_HS;                 // bf16 [512][832]
constexpr size_t SZ_ACT  = (size_t)B_ * ALD_ * 2;
constexpr size_t OFF_HFP = OFF_ACT + SZ_ACT;               // f32 [512][512]
constexpr size_t SZ_HFP  = (size_t)B_ * H_ * 4;
constexpr size_t OFF_WPT = OFF_HFP + SZ_HFP;               // bf16 [320][320]
constexpr size_t SZ_WPT  = (size_t)320 * 320 * 2;
constexpr size_t OFF_QPT = OFF_WPT + SZ_WPT;               // bf16 [320][512]
constexpr size_t SZ_QPT  = (size_t)320 * 512 * 2;
constexpr size_t OFF_RPT = OFF_QPT + SZ_QPT;               // bf16 [512][320]
constexpr size_t SZ_RPT  = (size_t)512 * 320 * 2;
constexpr size_t OFF_WGT = OFF_RPT + SZ_RPT;               // bf16 [2048][832]
constexpr size_t SZ_WGT  = (size_t)2048 * 832 * 2;
constexpr size_t OFF_BG  = OFF_WGT + SZ_WGT;               // f32 [2048]
constexpr size_t SZ_BG   = 2048 * 4;
constexpr size_t OFF_VT  = OFF_BG + SZ_BG;                 // bf16 [64][512]
constexpr size_t SZ_VT   = (size_t)64 * 512 * 2;
constexpr size_t OFF_BAR = OFF_VT + SZ_VT;                 // u32 flag vectors
constexpr size_t SZ_BAR  = 4096;
constexpr size_t WS_NEED = OFF_BAR + SZ_BAR;

// ---------------- helpers ----------------
DI unsigned short f2bf(float x) {
  unsigned int u = __float_as_uint(x);
  unsigned int r = (u + 0x7FFFu + ((u >> 16) & 1u)) >> 16;
  return (unsigned short)r;
}
DI float bf2f(unsigned short h) { return __uint_as_float(((unsigned int)h) << 16); }

DI float sigm(float x) {
  float e = __builtin_amdgcn_exp2f(x * -1.44269504088896f);
  return __builtin_amdgcn_rcpf(1.0f + e);
}
DI float tanh_(float x) {
  x = fminf(fmaxf(x, -15.0f), 15.0f);
  float e = __builtin_amdgcn_exp2f(x * 2.88539008177793f);
  return (e - 1.0f) * __builtin_amdgcn_rcpf(e + 1.0f);
}
DI bf16x8 asbf(s16x8 v) { return __builtin_bit_cast(bf16x8, v); }

// ---- LLC-coherent (sc0 sc1) accesses, compiler-managed (no inline asm) ----
DI unsigned long long ld_sys_u64(const void* p) {
  return __hip_atomic_load((const unsigned long long*)p, __ATOMIC_RELAXED,
                           __HIP_MEMORY_SCOPE_SYSTEM);
}
DI void st_sys_u64(void* p, unsigned long long v) {
  __hip_atomic_store((unsigned long long*)p, v, __ATOMIC_RELAXED,
                     __HIP_MEMORY_SCOPE_SYSTEM);
}
DI unsigned int ld_sys_u32(const unsigned int* p) {
  return __hip_atomic_load(p, __ATOMIC_RELAXED, __HIP_MEMORY_SCOPE_SYSTEM);
}
DI void st_sys_u32(unsigned int* p, unsigned int v) {
  __hip_atomic_store(p, v, __ATOMIC_RELAXED, __HIP_MEMORY_SCOPE_SYSTEM);
}
template<int N> DI void wait_vm() {          // pure wait, no outputs: hazard-free
  asm volatile("s_waitcnt vmcnt(%0)" :: "n"(N) : "memory");
}

struct a16x8 { unsigned long long lo, hi; };   // 16 bytes of A-operand
DI a16x8 ldA(const unsigned short* p) {
  a16x8 r; r.lo = ld_sys_u64(p); r.hi = ld_sys_u64(p + 4); return r;
}
DI void stA_lds(short* dst, a16x8 v) {
  *(unsigned long long*)dst = v.lo; *(unsigned long long*)(dst + 4) = v.hi;
}

// ---------------- GEMM core, KU k-tiles (of 32) per sync round ------------
// A: row-major [64][lda] bf16 via sc0sc1 u64 loads. B: row-major B^T [64][ldb]
// bf16, plain cached (L2-hot weights). 3-round-deep register prefetch gives
// ~2 rounds of slack to cover MALL latency. 256 threads, 4 waves 2x2,
// wave tile 32x32 (2x2 16x16x32 frags). LDS: 2 round-buffers of KU tiles.
template<int NK, int KU>
DI void gemmN(const unsigned short* Ab, int lda,
              const unsigned short* Bb, int ldb,
              short* sA, short* sB, f32x4 acc[2][2])
{
  constexpr int NR = (NK + KU - 1) / KU;   // sync rounds
  constexpr int RS = KU * 2048;            // shorts per round buffer
  const int tid  = threadIdx.x;
  const int lane = tid & 63;
  const int w = tid >> 6, wm = w >> 1, wn = w & 1;
  const unsigned short* ga = Ab + (tid >> 2) * lda + (tid & 3) * 8;
  const unsigned short* gb = Bb + (tid >> 2) * ldb + (tid & 3) * 8;
  const int arow0 = (wm * 32 + (lane & 15)) * 32 + (lane >> 4) * 8;
  const int brow0 = (wn * 32 + (lane & 15)) * 32 + (lane >> 4) * 8;

  a16x8 pa[3][KU];
  s16x8 pb[3][KU];
  // prologue: rounds 0..2 into reg sets 0..2; round 0 -> LDS buf 0
  #pragma unroll
  for (int r = 0; r < 3; ++r)
    #pragma unroll
    for (int q = 0; q < KU; ++q) {
      const int t = r * KU + q;
      if (t < NK) { pa[r][q] = ldA(ga + t * 32); pb[r][q] = *(const s16x8*)(gb + t * 32); }
    }
  #pragma unroll
  for (int q = 0; q < KU; ++q)
    if (q < NK) { stA_lds(&sA[q * 2048 + tid * 8], pa[0][q]);
                  *(s16x8*)&sB[q * 2048 + tid * 8] = pb[0][q]; }
  __syncthreads();
  #pragma unroll
  for (int j = 0; j < NR; ++j) {
    const int cur = (j & 1) * RS;
    // prefetch round j+3 into set j%3 (its round-j data is already in LDS)
    #pragma unroll
    for (int q = 0; q < KU; ++q) {
      const int t = (j + 3) * KU + q;
      if (t < NK) { pa[j % 3][q] = ldA(ga + t * 32); pb[j % 3][q] = *(const s16x8*)(gb + t * 32); }
    }
    // compute this round's KU tiles
    #pragma unroll
    for (int q = 0; q < KU; ++q) {
      if (j * KU + q < NK) {
        s16x8 A0 = *(const s16x8*)&sA[cur + q * 2048 + arow0];
        s16x8 A1 = *(const s16x8*)&sA[cur + q * 2048 + arow0 + 512];
        s16x8 B0 = *(const s16x8*)&sB[cur + q * 2048 + brow0];
        s16x8 B1 = *(const s16x8*)&sB[cur + q * 2048 + brow0 + 512];
        acc[0][0] = __builtin_amdgcn_mfma_f32_16x16x32_bf16(asbf(A0), asbf(B0), acc[0][0], 0, 0, 0);
        acc[0][1] = __builtin_amdgcn_mfma_f32_16x16x32_bf16(asbf(A0), asbf(B1), acc[0][1], 0, 0, 0);
        acc[1][0] = __builtin_amdgcn_mfma_f32_16x16x32_bf16(asbf(A1), asbf(B0), acc[1][0], 0, 0, 0);
        acc[1][1] = __builtin_amdgcn_mfma_f32_16x16x32_bf16(asbf(A1), asbf(B1), acc[1][1], 0, 0, 0);
      }
    }
    // stage round j+1 (reg set (j+1)%3, loaded at round j-2) into other buffer
    if (j + 1 < NR) {
      const int nxt = ((j + 1) & 1) * RS;
      #pragma unroll
      for (int q = 0; q < KU; ++q) {
        const int t = (j + 1) * KU + q;
        if (t < NK) { stA_lds(&sA[nxt + q * 2048 + tid * 8], pa[(j + 1) % 3][q]);
                      *(s16x8*)&sB[nxt + q * 2048 + tid * 8] = pb[(j + 1) % 3][q]; }
      }
    }
    __syncthreads();
  }
}

// Variant: A is fp32 (normal cached), K real = KREAL. Used by k_proj only.
template<int NK, int KREAL>
DI void gemm_f32A(const float* Af, int lda,
                  const unsigned short* Bb, int ldb,
                  short* sA, short* sB, f32x4 acc[2][2])
{
  const int tid  = threadIdx.x;
  const int lane = tid & 63;
  const int w = tid >> 6, wm = w >> 1, wn = w & 1;
  const float* ga = Af + (tid >> 2) * lda;
  const int cseg  = (tid & 3) * 8;
  const unsigned short* gb = Bb + (tid >> 2) * ldb + (tid & 3) * 8;
  const int arow0 = (wm * 32 + (lane & 15)) * 32 + (lane >> 4) * 8;
  const int brow0 = (wn * 32 + (lane & 15)) * 32 + (lane >> 4) * 8;

  auto loadA = [&](int k) -> s16x8 {
    s16x8 r;
    const int c0 = k * 32 + cseg;
    if (c0 + 8 <= KREAL) {
      float4 f0 = *(const float4*)(ga + c0);
      float4 f1 = *(const float4*)(ga + c0 + 4);
      r[0] = (short)f2bf(f0.x); r[1] = (short)f2bf(f0.y);
      r[2] = (short)f2bf(f0.z); r[3] = (short)f2bf(f0.w);
      r[4] = (short)f2bf(f1.x); r[5] = (short)f2bf(f1.y);
      r[6] = (short)f2bf(f1.z); r[7] = (short)f2bf(f1.w);
    } else {
      #pragma unroll
      for (int j = 0; j < 8; ++j) {
        float x = (c0 + j < KREAL) ? ga[c0 + j] : 0.0f;
        r[j] = (short)f2bf(x);
      }
    }
    return r;
  };

  s16x8 va = loadA(0);
  s16x8 vb = *(const s16x8*)gb;
  *(s16x8*)&sA[tid * 8] = va;
  *(s16x8*)&sB[tid * 8] = vb;
  __syncthreads();
  for (int k = 0; k < NK; ++k) {
    const int cur = (k & 1) * 2048;
    if (k + 1 < NK) {
      va = loadA(k + 1);
      vb = *(const s16x8*)(gb + (k + 1) * 32);
    }
    s16x8 a0 = *(const s16x8*)&sA[cur + arow0];
    s16x8 a1 = *(const s16x8*)&sA[cur + arow0 + 16 * 32];
    s16x8 b0 = *(const s16x8*)&sB[cur + brow0];
    s16x8 b1 = *(const s16x8*)&sB[cur + brow0 + 16 * 32];
    acc[0][0] = __builtin_amdgcn_mfma_f32_16x16x32_bf16(asbf(a0), asbf(b0), acc[0][0], 0, 0, 0);
    acc[0][1] = __builtin_amdgcn_mfma_f32_16x16x32_bf16(asbf(a0), asbf(b1), acc[0][1], 0, 0, 0);
    acc[1][0] = __builtin_amdgcn_mfma_f32_16x16x32_bf16(asbf(a1), asbf(b0), acc[1][0], 0, 0, 0);
    acc[1][1] = __builtin_amdgcn_mfma_f32_16x16x32_bf16(asbf(a1), asbf(b1), acc[1][1], 0, 0, 0);
    if (k + 1 < NK) {
      const int nxt = ((k + 1) & 1) * 2048;
      *(s16x8*)&sA[nxt + tid * 8] = va;
      *(s16x8*)&sB[nxt + tid * 8] = vb;
    }
    __syncthreads();
  }
}

// epilogue iterator: f(rowl, coll, acc_value) for the 64x64 block tile
template<typename F>
DI void epiloop(f32x4 acc[2][2], F&& f) {
  const int lane = threadIdx.x & 63;
  const int w = threadIdx.x >> 6, wm = w >> 1, wn = w & 1;
  #pragma unroll
  for (int mi = 0; mi < 2; ++mi)
    #pragma unroll
    for (int ni = 0; ni < 2; ++ni)
      #pragma unroll
      for (int r = 0; r < 4; ++r) {
        const int rowl = wm * 32 + mi * 16 + (lane >> 4) * 4 + r;
        const int coll = wn * 32 + ni * 16 + (lane & 15);
        f(rowl, coll, acc[mi][ni][r]);
      }
}

// pack-store a 64x64 u16 LDS tile to system memory as u64s (16 per row)
DI void pack_store_tile(const unsigned short* lds16, unsigned short* dstbase, int ldd) {
  const unsigned long long* l64 = (const unsigned long long*)lds16;
  #pragma unroll
  for (int it = 0; it < 4; ++it) {
    const int i = it * 256 + threadIdx.x;
    const int row = i >> 4, q = i & 15;
    st_sys_u64(dstbase + row * ldd + q * 4, l64[row * 16 + q]);
  }
}

// ---------------- prep kernels ----------------
__global__ void k_prep_wpt(const float* __restrict__ Wi, unsigned short* __restrict__ WpT) {
  int i = blockIdx.x * 256 + threadIdx.x;
  if (i >= 320 * 320) return;
  int n = i / 320, k = i % 320;
  float v = (n < 300 && k < 300) ? Wi[k * 300 + n] : 0.0f;
  WpT[i] = f2bf(v);
}
__global__ void k_prep_qpt(const float* __restrict__ Q, unsigned short* __restrict__ QpT) {
  int i = blockIdx.x * 256 + threadIdx.x;
  if (i >= 320 * 512) return;
  int n = i >> 9, k = i & 511;
  float v = (n < 300) ? Q[k * 300 + n] : 0.0f;
  QpT[i] = f2bf(v);
}
__global__ void k_prep_rpt(const float* __restrict__ R, unsigned short* __restrict__ RpT) {
  int i = blockIdx.x * 256 + threadIdx.x;
  if (i >= 512 * 320) return;
  int n = i / 320, k = i % 320;
  float v = (k < 300) ? R[k * 512 + n] : 0.0f;
  RpT[i] = f2bf(v);
}
__global__ void k_prep_wgt(const float* __restrict__ Wih, const float* __restrict__ Whh,
                           unsigned short* __restrict__ WgT) {
  int i = blockIdx.x * 256 + threadIdx.x;
  if (i >= 2048 * 832) return;
  int np = i / 832, k = i % 832;
  int c = np >> 2, g = np & 3, col = g * 512 + c;
  float v = 0.0f;
  if (k < 300) v = Wih[k * 2048 + col];
  else if (k >= 320) v = Whh[(k - 320) * 2048 + col];
  WgT[i] = f2bf(v);
}
__global__ void k_prep_bg(const float* __restrict__ bih, const float* __restrict__ bhh,
                          float* __restrict__ bg) {
  int i = blockIdx.x * 256 + threadIdx.x;
  if (i >= 2048) return;
  int c = i >> 2, g = i & 3, col = g * 512 + c;
  bg[i] = bih[col] + bhh[col];
}
__global__ void k_prep_vt(const float* __restrict__ Wc3, const float* __restrict__ Wc4,
                          const float* __restrict__ Wc5, unsigned short* __restrict__ VT) {
  int i = blockIdx.x * 256 + threadIdx.x;
  if (i >= 64 * 512) return;
  int j = i >> 9, k = i & 511;
  float v = 0.0f;
  if (j < 9)       { int f = j / 3,  dt = j % 3;        v = Wc3[(f * 3 + dt) * 512 + k]; }
  else if (j < 21) { int jj = j - 9;  int f = jj / 4, dt = jj % 4; v = Wc4[(f * 4 + dt) * 512 + k]; }
  else if (j < 36) { int jj = j - 21; int f = jj / 5, dt = jj % 5; v = Wc5[(f * 5 + dt) * 512 + k]; }
  VT[i] = f2bf(v);
}
__global__ void k_wsfail(float* out, int n, float v) {
  int i = blockIdx.x * 256 + threadIdx.x;
  if (i < n) out[i] = -v;
}

// ---------------- input projection ----------------
__global__ __launch_bounds__(256) void k_proj(const float* __restrict__ x,
                                              const unsigned short* __restrict__ WpT,
                                              const float* __restrict__ b_in,
                                              unsigned short* __restrict__ xin) {
  __shared__ short sA[4096], sB[4096];
  const int m0 = blockIdx.x * 64, n0 = blockIdx.y * 64;
  f32x4 acc[2][2];
  const f32x4 z = {0.f, 0.f, 0.f, 0.f};
  acc[0][0] = z; acc[0][1] = z; acc[1][0] = z; acc[1][1] = z;
  gemm_f32A<10, 300>(x + (size_t)m0 * 300, 300, WpT + n0 * 320, 320, sA, sB, acc);
  epiloop(acc, [&](int rowl, int coll, float vacc) {
    const int row = m0 + rowl, col = n0 + coll;
    float o = 0.0f;
    if (col < 300) o = tanh_(vacc + b_in[col]);
    const int b = row >> 8, s = row & 255;
    xin[(size_t)(s * 512 + b) * KP_ + col] = f2bf(o);
  });
}

// ---------------- persistent scan kernel ----------------
// 256 WGs x 256 threads in 8 independent groups of 32 WGs; group g owns batch
// rows 64g..64g+63 for all phases. Cross-WG data (act, hs, hfp) moves only
// through sc0sc1 (LLC-coherent) loads/stores -> no cache fences, weights stay
// L2-hot. Barrier: per-WG epoch-flag stores in one 128B line + 64-lane poll.
__global__ __launch_bounds__(256) void k_scan(
    const unsigned short* __restrict__ xin,
    const unsigned short* __restrict__ QpT,
    const unsigned short* __restrict__ RpT,
    const unsigned short* __restrict__ WgT,
    const float* __restrict__ bg,
    const unsigned short* __restrict__ VT,
    unsigned short* __restrict__ hs,
    unsigned short* __restrict__ act,
    float* __restrict__ hfp,
    float* __restrict__ U,
    unsigned int* __restrict__ bar)
{
  __shared__ short sA[16384], sB[16384];   // 2 round-buffers x 4 tiles x 4KB
  __shared__ float gbuf[4096];
  const int wg   = blockIdx.x;
  const int grp  = wg >> 5;       // batch-row group: rows 64*grp .. 64*grp+63
  const int l    = wg & 31;       // lane-in-group
  const int tid  = threadIdx.x;
  const int lane = tid & 63;
  const f32x4 z = {0.f, 0.f, 0.f, 0.f};

  // gates tile assignment (static across steps -> cell state in registers)
  const int gm0 = grp * 64;             // batch-row tile
  const int gn0 = l * 64;               // gate-col tile (permuted n' = 4c+g)
  float c_state[4] = {0.f, 0.f, 0.f, 0.f};

  unsigned int* flags = bar + grp * 32;   // this group's 128B flag line
  int ep = 0;  // barrier epoch
  auto bar_sync = [&]() {
    wait_vm<0>();        // each wave drains its own system-stores to LLC
    __syncthreads();     // all waves of this WG drained
    const unsigned tag = (unsigned)(ep + 1);
    if (tid == 0) st_sys_u32(&flags[l], tag);
    // all waves poll the whole flag line (one MALL load per lane)
    while (!__all(ld_sys_u32(&flags[lane & 31]) >= tag))
      __builtin_amdgcn_s_sleep(2);
    ++ep;
  };

  for (int t = 0; t < S_; ++t) {
    const unsigned short* hst = hs + (size_t)(t % NRING) * HSLOT;
    unsigned short*       hso = hs + (size_t)((t + 1) % NRING) * HSLOT;

    // ---- P1: act[g rows, 0:320] = 2*sigm(h_{t-1} @ Q) * xin_t  (5 tiles)
    if (l < 5) {
      const int m0 = gm0, n0 = l * 64;
      f32x4 acc[2][2];
      acc[0][0] = z; acc[0][1] = z; acc[1][0] = z; acc[1][1] = z;
      gemmN<16, 4>(hst + m0 * 512, 512, QpT + n0 * 512, 512, sA, sB, acc);
      const unsigned short* xin_t = xin + (size_t)t * 512 * KP_;
      unsigned short* g16 = (unsigned short*)gbuf;
      epiloop(acc, [&](int rowl, int coll, float vacc) {
        const int row = m0 + rowl, col = n0 + coll;
        g16[rowl * 64 + coll] = f2bf(2.0f * sigm(vacc) * bf2f(xin_t[row * KP_ + col]));
      });
      __syncthreads();
      pack_store_tile(g16, act + m0 * ALD_ + n0, ALD_);
    }
    bar_sync();

    // ---- P2: act[g rows, 320:832] = 2*sigm(xt @ R) * hfp  (8 tiles)
    if (l < 8) {
      const int m0 = gm0, n0 = l * 64;
      // cooperative hfp tile load into gbuf (latency hides under the GEMM)
      unsigned long long* g64 = (unsigned long long*)gbuf;
      #pragma unroll
      for (int it = 0; it < 8; ++it) {
        const int i = it * 256 + tid;
        const int row = i >> 5, p = i & 31;
        g64[row * 32 + p] = ld_sys_u64(hfp + (m0 + row) * 512 + n0 + p * 2);
      }
      f32x4 acc[2][2];
      acc[0][0] = z; acc[0][1] = z; acc[1][0] = z; acc[1][1] = z;
      gemmN<10, 4>(act + m0 * ALD_, ALD_, RpT + n0 * KP_, KP_, sA, sB, acc);
      unsigned short* g16 = (unsigned short*)sA;   // sA free after gemm
      epiloop(acc, [&](int rowl, int coll, float vacc) {
        g16[rowl * 64 + coll] = f2bf(2.0f * sigm(vacc) * gbuf[rowl * 64 + coll]);
      });
      __syncthreads();
      pack_store_tile(g16, act + m0 * ALD_ + 320 + n0, ALD_);
    }
    bar_sync();

    // ---- P3: gates GEMM + cell update (32 tiles, Ct in registers)
    {
      f32x4 acc[2][2];
      acc[0][0] = z; acc[0][1] = z; acc[1][0] = z; acc[1][1] = z;
      gemmN<26, 4>(act + gm0 * ALD_, ALD_, WgT + gn0 * 832, 832, sA, sB, acc);
      epiloop(acc, [&](int rowl, int coll, float vacc) {
        gbuf[rowl * 64 + coll] = vacc;
      });
      unsigned short* hbuf = (unsigned short*)sA;  // 64x16 u16 (free after gemm)
      float*          fbuf = (float*)sB;           // 64x16 f32
      __syncthreads();
      #pragma unroll
      for (int q = 0; q < 4; ++q) {
        const int item = q * 256 + tid;
        const int row = item >> 4, cu = item & 15;
        const float4 bb = *(const float4*)&bg[gn0 + cu * 4];
        const float iv = gbuf[row * 64 + cu * 4 + 0] + bb.x;
        const float fv = gbuf[row * 64 + cu * 4 + 1] + bb.y;
        const float gv = gbuf[row * 64 + cu * 4 + 2] + bb.z;
        const float ov = gbuf[row * 64 + cu * 4 + 3] + bb.w;
        const float cn = sigm(fv) * c_state[q] + sigm(iv) * tanh_(gv);
        const float h  = sigm(ov) * tanh_(cn);
        c_state[q] = cn;
        hbuf[row * 16 + cu] = f2bf(h);
        fbuf[row * 16 + cu] = h;
      }
      __syncthreads();
      // pack-store h (64x16 u16 = 256 u64) and hfp (64x16 f32 = 512 u64)
      {
        const unsigned long long* h64 = (const unsigned long long*)hbuf;
        const int row = tid >> 2, q = tid & 3;
        st_sys_u64(hso + (gm0 + row) * 512 + (gn0 >> 2) + q * 4, h64[row * 4 + q]);
        const unsigned long long* f64 = (const unsigned long long*)fbuf;
        #pragma unroll
        for (int it = 0; it < 2; ++it) {
          const int i = it * 256 + tid;
          const int r2 = i >> 3, p = i & 7;
          st_sys_u64(hfp + (gm0 + r2) * 512 + (gn0 >> 2) + p * 2, f64[r2 * 8 + p]);
        }
      }
      __syncthreads();
    }
    bar_sync();

    // ---- convU every 32 steps: group handles its own 64 rows x 32 timesteps
    if ((t & 31) == 31) {
      const int c = t >> 5;
      const int tglob = 32 * c + l;
      const int slot = (tglob + 1) % NRING;
      const int brow = gm0;
      f32x4 acc[2][2];
      acc[0][0] = z; acc[0][1] = z; acc[1][0] = z; acc[1][1] = z;
      gemmN<16, 4>(hs + (size_t)slot * HSLOT + (size_t)brow * 512, 512, VT, 512, sA, sB, acc);
      epiloop(acc, [&](int rowl, int coll, float vacc) {
        U[((size_t)(brow + rowl) * 256 + tglob) * 64 + coll] = vacc;
      });
    }
  }
}

// window-sum + relu + global max pool + final linear
__global__ __launch_bounds__(256) void k_combine(const float* __restrict__ U,
                                                 const float* __restrict__ bc3,
                                                 const float* __restrict__ bc4,
                                                 const float* __restrict__ bc5,
                                                 const float* __restrict__ Wl,
                                                 const float* __restrict__ bl,
                                                 float* __restrict__ out) {
  const int b = blockIdx.x;
  const int p = threadIdx.x;
  const float* Ub = U + (size_t)b * (256 * 64);
  float v[9];
  #pragma unroll
  for (int j = 0; j < 9; ++j) v[j] = -1e30f;
  if (p < 254) {
    #pragma unroll
    for (int f = 0; f < 3; ++f)
      v[f] = Ub[(p + 0) * 64 + f * 3 + 0] + Ub[(p + 1) * 64 + f * 3 + 1] + Ub[(p + 2) * 64 + f * 3 + 2];
  }
  if (p < 253) {
    #pragma unroll
    for (int f = 0; f < 3; ++f)
      v[3 + f] = Ub[(p + 0) * 64 + 9 + f * 4 + 0] + Ub[(p + 1) * 64 + 9 + f * 4 + 1] +
                 Ub[(p + 2) * 64 + 9 + f * 4 + 2] + Ub[(p + 3) * 64 + 9 + f * 4 + 3];
  }
  if (p < 252) {
    #pragma unroll
    for (int f = 0; f < 3; ++f)
      v[6 + f] = Ub[(p + 0) * 64 + 21 + f * 5 + 0] + Ub[(p + 1) * 64 + 21 + f * 5 + 1] +
                 Ub[(p + 2) * 64 + 21 + f * 5 + 2] + Ub[(p + 3) * 64 + 21 + f * 5 + 3] +
                 Ub[(p + 4) * 64 + 21 + f * 5 + 4];
  }
  __shared__ float red[4][9];
  const int lane = threadIdx.x & 63, w = threadIdx.x >> 6;
  #pragma unroll
  for (int j = 0; j < 9; ++j) {
    float m = v[j];
    #pragma unroll
    for (int off = 32; off >= 1; off >>= 1) m = fmaxf(m, __shfl_xor(m, off));
    if (lane == 0) red[w][j] = m;
  }
  __syncthreads();
  if (threadIdx.x < 2) {
    const int k = threadIdx.x;
    float o = bl[k];
    #pragma unroll
    for (int j = 0; j < 9; ++j) {
      float m = fmaxf(fmaxf(red[0][j], red[1][j]), fmaxf(red[2][j], red[3][j]));
      float bias = (j < 3) ? bc3[j] : (j < 6) ? bc4[j - 3] : bc5[j - 6];
      o += fmaxf(m + bias, 0.0f) * Wl[j * 2 + k];
    }
    out[b * 2 + k] = o;
  }
}

// ---------------- host launch ----------------
extern "C" void kernel_launch(void* const* d_in, const int* in_sizes, int n_in,
                              void* d_out, int out_size, void* d_ws, size_t ws_size,
                              hipStream_t stream) {
  const float* x     = (const float*)d_in[0];
  const float* W_in  = (const float*)d_in[1];
  const float* b_in  = (const float*)d_in[2];
  const float* Wih   = (const float*)d_in[3];
  const float* Whh   = (const float*)d_in[4];
  const float* bih   = (const float*)d_in[5];
  const float* bhh   = (const float*)d_in[6];
  const float* Q     = (const float*)d_in[7];
  const float* R     = (const float*)d_in[8];
  const float* Wc3   = (const float*)d_in[9];
  const float* bc3   = (const float*)d_in[10];
  const float* Wc4   = (const float*)d_in[11];
  const float* bc4   = (const float*)d_in[12];
  const float* Wc5   = (const float*)d_in[13];
  const float* bc5   = (const float*)d_in[14];
  const float* W_lin = (const float*)d_in[15];
  const float* b_lin = (const float*)d_in[16];

  if (ws_size < WS_NEED) {  // diagnosable marker: absmax ≈ ws_size in MB
    k_wsfail<<<4, 256, 0, stream>>>((float*)d_out, out_size, (float)(ws_size >> 20));
    return;
  }

  char* ws = (char*)d_ws;
  unsigned short* xin = (unsigned short*)(ws + OFF_XIN);
  float*          U   = (float*)(ws + OFF_U);
  unsigned short* hs  = (unsigned short*)(ws + OFF_HS);
  unsigned short* act = (unsigned short*)(ws + OFF_ACT);
  float*          hfp = (float*)(ws + OFF_HFP);
  unsigned short* WpT = (unsigned short*)(ws + OFF_WPT);
  unsigned short* QpT = (unsigned short*)(ws + OFF_QPT);
  unsigned short* RpT = (unsigned short*)(ws + OFF_RPT);
  unsigned short* WgT = (unsigned short*)(ws + OFF_WGT);
  float*          bg  = (float*)(ws + OFF_BG);
  unsigned short* VT  = (unsigned short*)(ws + OFF_VT);
  unsigned int*   bar = (unsigned int*)(ws + OFF_BAR);

  // per-replay init: h0 = c0 = 0 (ring slot 0 + hfp), barrier flags = 0
  (void)hipMemsetAsync(hs, 0, HSLOT * 2, stream);
  (void)hipMemsetAsync(hfp, 0, SZ_HFP, stream);
  (void)hipMemsetAsync(bar, 0, SZ_BAR, stream);

  // weight prep
  k_prep_wpt<<<(320 * 320 + 255) / 256, 256, 0, stream>>>(W_in, WpT);
  k_prep_qpt<<<(320 * 512 + 255) / 256, 256, 0, stream>>>(Q, QpT);
  k_prep_rpt<<<(512 * 320 + 255) / 256, 256, 0, stream>>>(R, RpT);
  k_prep_wgt<<<(2048 * 832 + 255) / 256, 256, 0, stream>>>(Wih, Whh, WgT);
  k_prep_bg<<<8, 256, 0, stream>>>(bih, bhh, bg);
  k_prep_vt<<<(64 * 512 + 255) / 256, 256, 0, stream>>>(Wc3, Wc4, Wc5, VT);

  // input projection
  k_proj<<<dim3(131072 / 64, KP_ / 64), 256, 0, stream>>>(x, WpT, b_in, xin);

  // persistent scan (entire 256-step recurrence in one dispatch)
  k_scan<<<NWG, 256, 0, stream>>>(xin, QpT, RpT, WgT, bg, VT, hs, act, hfp, U, bar);

  // conv window-max + final linear
  k_combine<<<512, 256, 0, stream>>>(U, bc3, bc4, bc5, W_lin, b_lin, (float*)d_out);
}

// Round 9
// 5489.967 us; speedup vs baseline: 1.2591x; 1.2591x over previous
//
#include <hip/hip_runtime.h>

#define DI __device__ __forceinline__

typedef __attribute__((ext_vector_type(4))) float  f32x4;
typedef __attribute__((ext_vector_type(8))) short  s16x8;
typedef __attribute__((ext_vector_type(8))) __bf16 bf16x8;
typedef unsigned long long u64;

// ---------------- constants ----------------
constexpr int S_   = 256;
constexpr int B_   = 512;
constexpr int H_   = 512;
constexpr int KP_  = 320;   // padded 300
constexpr int ALD_ = 832;   // act row: [xt 0..320 | htm 320..832]
constexpr int NRING = 34;
constexpr int NWG  = 256;   // persistent workgroups (== CU count)
constexpr size_t HSLOT = 512 * 512;  // elements per hs slot

// ---------------- workspace layout (bytes) ----------------
constexpr size_t OFF_XIN = 0;                              // bf16 [S][B][320]
constexpr size_t SZ_XIN  = (size_t)S_ * B_ * KP_ * 2;
constexpr size_t OFF_U   = OFF_XIN + SZ_XIN;               // f32 [B][S][64]
constexpr size_t SZ_U    = (size_t)B_ * S_ * 64 * 4;
constexpr size_t OFF_HS  = OFF_U + SZ_U;                   // bf16 ring [34][512][512]
constexpr size_t SZ_HS   = (size_t)NRING * HSLOT * 2;
constexpr size_t OFF_ACT = OFF_HS + SZ_HS;                 // bf16 [512][832]
constexpr size_t SZ_ACT  = (size_t)B_ * ALD_ * 2;
constexpr size_t OFF_HFP = OFF_ACT + SZ_ACT;               // f32 [512][512]
constexpr size_t SZ_HFP  = (size_t)B_ * H_ * 4;
constexpr size_t OFF_WPT = OFF_HFP + SZ_HFP;               // bf16 [320][320]
constexpr size_t SZ_WPT  = (size_t)320 * 320 * 2;
constexpr size_t OFF_QPT = OFF_WPT + SZ_WPT;               // bf16 [320][512]
constexpr size_t SZ_QPT  = (size_t)320 * 512 * 2;
constexpr size_t OFF_RPT = OFF_QPT + SZ_QPT;               // bf16 [512][320]
constexpr size_t SZ_RPT  = (size_t)512 * 320 * 2;
constexpr size_t OFF_WGT = OFF_RPT + SZ_RPT;               // bf16 [2048][832]
constexpr size_t SZ_WGT  = (size_t)2048 * 832 * 2;
constexpr size_t OFF_BG  = OFF_WGT + SZ_WGT;               // f32 [2048]
constexpr size_t SZ_BG   = 2048 * 4;
constexpr size_t OFF_VT  = OFF_BG + SZ_BG;                 // bf16 [64][512]
constexpr size_t SZ_VT   = (size_t)64 * 512 * 2;
constexpr size_t OFF_BAR = OFF_VT + SZ_VT;                 // u32 barrier counters
constexpr size_t SZ_BAR  = 4096;
constexpr size_t WS_NEED = OFF_BAR + SZ_BAR;

// ---------------- helpers ----------------
DI unsigned short f2bf(float x) {
  unsigned int u = __float_as_uint(x);
  unsigned int r = (u + 0x7FFFu + ((u >> 16) & 1u)) >> 16;
  return (unsigned short)r;
}
DI float bf2f(unsigned short h) { return __uint_as_float(((unsigned int)h) << 16); }

DI float sigm(float x) {
  float e = __builtin_amdgcn_exp2f(x * -1.44269504088896f);
  return __builtin_amdgcn_rcpf(1.0f + e);
}
DI float tanh_(float x) {
  x = fminf(fmaxf(x, -15.0f), 15.0f);
  float e = __builtin_amdgcn_exp2f(x * 2.88539008177793f);
  return (e - 1.0f) * __builtin_amdgcn_rcpf(e + 1.0f);
}
DI bf16x8 asbf(s16x8 v) { return __builtin_bit_cast(bf16x8, v); }

// ---- LLC-coherent (sc0 sc1) accesses, compiler-managed (no inline asm) ----
DI u64 ld_sys_u64(const void* p) {
  return __hip_atomic_load((const u64*)p, __ATOMIC_RELAXED, __HIP_MEMORY_SCOPE_SYSTEM);
}
DI void st_sys_u64(void* p, u64 v) {
  __hip_atomic_store((u64*)p, v, __ATOMIC_RELAXED, __HIP_MEMORY_SCOPE_SYSTEM);
}
template<int N> DI void wait_vm() {          // pure wait, no outputs: hazard-free
  asm volatile("s_waitcnt vmcnt(%0)" :: "n"(N) : "memory");
}

struct a16x8 { u64 lo, hi; };   // 16 bytes of A-operand
DI a16x8 ldA(const unsigned short* p) {
  a16x8 r; r.lo = ld_sys_u64(p); r.hi = ld_sys_u64(p + 4); return r;
}
DI void stA_lds(short* dst, a16x8 v) {
  *(u64*)dst = v.lo; *(u64*)(dst + 4) = v.hi;
}

// ---------------- dual-team GEMM core (512 threads) -----------------------
// Teams: waves 0-3 (tid<256) process even k-tiles, waves 4-7 odd k-tiles,
// each into its own acc. K = NR*64 (NR rounds x 2 tiles). A via sc0sc1 u64
// (MALL), B plain cached (L2-hot weights). Depth-2 round prefetch, two reg
// sets by parity (16 VGPRs of state - compiler keeps them live, R6-proven).
// Per-team wave tile 32x32 (2x2 16x16x32 frags) of the 64x64 block tile.
// LDS: sA/sB = 2 round-buffers x 2 team slots x 2048 shorts (16KB each).
template<int NR>
DI void gemm2(const unsigned short* Ab, int lda,
              const unsigned short* Bb, int ldb,
              short* sA, short* sB, f32x4 acc[2][2])
{
  const int tid  = threadIdx.x;
  const int t2   = tid & 255;
  const int team = tid >> 8;
  const int lane = t2 & 63;
  const int w = t2 >> 6, wm = w >> 1, wn = w & 1;
  const unsigned short* ga = Ab + (t2 >> 2) * lda + (t2 & 3) * 8;
  const unsigned short* gb = Bb + (t2 >> 2) * ldb + (t2 & 3) * 8;
  const int slot  = team * 2048;
  const int arow0 = (wm * 32 + (lane & 15)) * 32 + (lane >> 4) * 8;
  const int brow0 = (wn * 32 + (lane & 15)) * 32 + (lane >> 4) * 8;

  a16x8 a0, a1 = {};
  s16x8 b0, b1 = {};
  a0 = ldA(ga + team * 32);                       // round 0: kt = team
  b0 = *(const s16x8*)(gb + team * 32);
  if (NR > 1) {
    a1 = ldA(ga + (2 + team) * 32);               // round 1: kt = 2+team
    b1 = *(const s16x8*)(gb + (2 + team) * 32);
  }
  stA_lds(&sA[slot + t2 * 8], a0);
  *(s16x8*)&sB[slot + t2 * 8] = b0;
  __syncthreads();
  #pragma unroll
  for (int j = 0; j < NR; ++j) {
    const int cur = (j & 1) * 4096;
    if (j + 2 < NR) {                             // prefetch round j+2 into set j&1
      const int kt = 2 * (j + 2) + team;
      if ((j & 1) == 0) { a0 = ldA(ga + kt * 32); b0 = *(const s16x8*)(gb + kt * 32); }
      else              { a1 = ldA(ga + kt * 32); b1 = *(const s16x8*)(gb + kt * 32); }
    }
    s16x8 A0 = *(const s16x8*)&sA[cur + slot + arow0];
    s16x8 A1 = *(const s16x8*)&sA[cur + slot + arow0 + 512];
    s16x8 B0 = *(const s16x8*)&sB[cur + slot + brow0];
    s16x8 B1 = *(const s16x8*)&sB[cur + slot + brow0 + 512];
    acc[0][0] = __builtin_amdgcn_mfma_f32_16x16x32_bf16(asbf(A0), asbf(B0), acc[0][0], 0, 0, 0);
    acc[0][1] = __builtin_amdgcn_mfma_f32_16x16x32_bf16(asbf(A0), asbf(B1), acc[0][1], 0, 0, 0);
    acc[1][0] = __builtin_amdgcn_mfma_f32_16x16x32_bf16(asbf(A1), asbf(B0), acc[1][0], 0, 0, 0);
    acc[1][1] = __builtin_amdgcn_mfma_f32_16x16x32_bf16(asbf(A1), asbf(B1), acc[1][1], 0, 0, 0);
    if (j + 1 < NR) {                             // stage round j+1 (set (j+1)&1)
      const int nxt = ((j + 1) & 1) * 4096;
      if ((j & 1) == 0) { stA_lds(&sA[nxt + slot + t2 * 8], a1); *(s16x8*)&sB[nxt + slot + t2 * 8] = b1; }
      else              { stA_lds(&sA[nxt + slot + t2 * 8], a0); *(s16x8*)&sB[nxt + slot + t2 * 8] = b0; }
    }
    __syncthreads();
  }
}

// team1 acc -> rbuf [16][256] (stride-1, conflict-free), team0 adds into acc
DI void reduce_teams(f32x4 acc[2][2], float* rbuf) {
  const int tid = threadIdx.x, t2 = tid & 255;
  if (tid >= 256) {
    #pragma unroll
    for (int mi = 0; mi < 2; ++mi)
      #pragma unroll
      for (int ni = 0; ni < 2; ++ni)
        #pragma unroll
        for (int r = 0; r < 4; ++r)
          rbuf[((mi * 2 + ni) * 4 + r) * 256 + t2] = acc[mi][ni][r];
  }
  __syncthreads();
  if (tid < 256) {
    #pragma unroll
    for (int mi = 0; mi < 2; ++mi)
      #pragma unroll
      for (int ni = 0; ni < 2; ++ni)
        #pragma unroll
        for (int r = 0; r < 4; ++r)
          acc[mi][ni][r] += rbuf[((mi * 2 + ni) * 4 + r) * 256 + t2];
  }
}

// Variant: A is fp32 (normal cached), K real = KREAL. Used by k_proj only (256 thr).
template<int NK, int KREAL>
DI void gemm_f32A(const float* Af, int lda,
                  const unsigned short* Bb, int ldb,
                  short* sA, short* sB, f32x4 acc[2][2])
{
  const int tid  = threadIdx.x;
  const int lane = tid & 63;
  const int w = tid >> 6, wm = w >> 1, wn = w & 1;
  const float* ga = Af + (tid >> 2) * lda;
  const int cseg  = (tid & 3) * 8;
  const unsigned short* gb = Bb + (tid >> 2) * ldb + (tid & 3) * 8;
  const int arow0 = (wm * 32 + (lane & 15)) * 32 + (lane >> 4) * 8;
  const int brow0 = (wn * 32 + (lane & 15)) * 32 + (lane >> 4) * 8;

  auto loadA = [&](int k) -> s16x8 {
    s16x8 r;
    const int c0 = k * 32 + cseg;
    if (c0 + 8 <= KREAL) {
      float4 f0 = *(const float4*)(ga + c0);
      float4 f1 = *(const float4*)(ga + c0 + 4);
      r[0] = (short)f2bf(f0.x); r[1] = (short)f2bf(f0.y);
      r[2] = (short)f2bf(f0.z); r[3] = (short)f2bf(f0.w);
      r[4] = (short)f2bf(f1.x); r[5] = (short)f2bf(f1.y);
      r[6] = (short)f2bf(f1.z); r[7] = (short)f2bf(f1.w);
    } else {
      #pragma unroll
      for (int j = 0; j < 8; ++j) {
        float x = (c0 + j < KREAL) ? ga[c0 + j] : 0.0f;
        r[j] = (short)f2bf(x);
      }
    }
    return r;
  };

  s16x8 va = loadA(0);
  s16x8 vb = *(const s16x8*)gb;
  *(s16x8*)&sA[tid * 8] = va;
  *(s16x8*)&sB[tid * 8] = vb;
  __syncthreads();
  for (int k = 0; k < NK; ++k) {
    const int cur = (k & 1) * 2048;
    if (k + 1 < NK) {
      va = loadA(k + 1);
      vb = *(const s16x8*)(gb + (k + 1) * 32);
    }
    s16x8 a0 = *(const s16x8*)&sA[cur + arow0];
    s16x8 a1 = *(const s16x8*)&sA[cur + arow0 + 16 * 32];
    s16x8 b0 = *(const s16x8*)&sB[cur + brow0];
    s16x8 b1 = *(const s16x8*)&sB[cur + brow0 + 16 * 32];
    acc[0][0] = __builtin_amdgcn_mfma_f32_16x16x32_bf16(asbf(a0), asbf(b0), acc[0][0], 0, 0, 0);
    acc[0][1] = __builtin_amdgcn_mfma_f32_16x16x32_bf16(asbf(a0), asbf(b1), acc[0][1], 0, 0, 0);
    acc[1][0] = __builtin_amdgcn_mfma_f32_16x16x32_bf16(asbf(a1), asbf(b0), acc[1][0], 0, 0, 0);
    acc[1][1] = __builtin_amdgcn_mfma_f32_16x16x32_bf16(asbf(a1), asbf(b1), acc[1][1], 0, 0, 0);
    if (k + 1 < NK) {
      const int nxt = ((k + 1) & 1) * 2048;
      *(s16x8*)&sA[nxt + tid * 8] = va;
      *(s16x8*)&sB[nxt + tid * 8] = vb;
    }
    __syncthreads();
  }
}

// epilogue iterator over team0's 64x64 tile: f(rowl, coll, acc_value)
template<typename F>
DI void epiloop(f32x4 acc[2][2], F&& f) {
  const int lane = threadIdx.x & 63;
  const int w = (threadIdx.x & 255) >> 6, wm = w >> 1, wn = w & 1;
  #pragma unroll
  for (int mi = 0; mi < 2; ++mi)
    #pragma unroll
    for (int ni = 0; ni < 2; ++ni)
      #pragma unroll
      for (int r = 0; r < 4; ++r) {
        const int rowl = wm * 32 + mi * 16 + (lane >> 4) * 4 + r;
        const int coll = wn * 32 + ni * 16 + (lane & 15);
        f(rowl, coll, acc[mi][ni][r]);
      }
}

// pack-store a 64x64 u16 LDS tile to system memory as u64s (512 threads)
DI void pack_store_512(const unsigned short* lds16, unsigned short* dstbase, int ldd) {
  const u64* l64 = (const u64*)lds16;
  #pragma unroll
  for (int it = 0; it < 2; ++it) {
    const int i = it * 512 + threadIdx.x;
    const int row = i >> 4, q = i & 15;
    st_sys_u64(dstbase + row * ldd + q * 4, l64[row * 16 + q]);
  }
}

// ---------------- prep kernels ----------------
__global__ void k_prep_wpt(const float* __restrict__ Wi, unsigned short* __restrict__ WpT) {
  int i = blockIdx.x * 256 + threadIdx.x;
  if (i >= 320 * 320) return;
  int n = i / 320, k = i % 320;
  float v = (n < 300 && k < 300) ? Wi[k * 300 + n] : 0.0f;
  WpT[i] = f2bf(v);
}
__global__ void k_prep_qpt(const float* __restrict__ Q, unsigned short* __restrict__ QpT) {
  int i = blockIdx.x * 256 + threadIdx.x;
  if (i >= 320 * 512) return;
  int n = i >> 9, k = i & 511;
  float v = (n < 300) ? Q[k * 300 + n] : 0.0f;
  QpT[i] = f2bf(v);
}
__global__ void k_prep_rpt(const float* __restrict__ R, unsigned short* __restrict__ RpT) {
  int i = blockIdx.x * 256 + threadIdx.x;
  if (i >= 512 * 320) return;
  int n = i / 320, k = i % 320;
  float v = (k < 300) ? R[k * 512 + n] : 0.0f;
  RpT[i] = f2bf(v);
}
__global__ void k_prep_wgt(const float* __restrict__ Wih, const float* __restrict__ Whh,
                           unsigned short* __restrict__ WgT) {
  int i = blockIdx.x * 256 + threadIdx.x;
  if (i >= 2048 * 832) return;
  int np = i / 832, k = i % 832;
  int c = np >> 2, g = np & 3, col = g * 512 + c;
  float v = 0.0f;
  if (k < 300) v = Wih[k * 2048 + col];
  else if (k >= 320) v = Whh[(k - 320) * 2048 + col];
  WgT[i] = f2bf(v);
}
__global__ void k_prep_bg(const float* __restrict__ bih, const float* __restrict__ bhh,
                          float* __restrict__ bg) {
  int i = blockIdx.x * 256 + threadIdx.x;
  if (i >= 2048) return;
  int c = i >> 2, g = i & 3, col = g * 512 + c;
  bg[i] = bih[col] + bhh[col];
}
__global__ void k_prep_vt(const float* __restrict__ Wc3, const float* __restrict__ Wc4,
                          const float* __restrict__ Wc5, unsigned short* __restrict__ VT) {
  int i = blockIdx.x * 256 + threadIdx.x;
  if (i >= 64 * 512) return;
  int j = i >> 9, k = i & 511;
  float v = 0.0f;
  if (j < 9)       { int f = j / 3,  dt = j % 3;        v = Wc3[(f * 3 + dt) * 512 + k]; }
  else if (j < 21) { int jj = j - 9;  int f = jj / 4, dt = jj % 4; v = Wc4[(f * 4 + dt) * 512 + k]; }
  else if (j < 36) { int jj = j - 21; int f = jj / 5, dt = jj % 5; v = Wc5[(f * 5 + dt) * 512 + k]; }
  VT[i] = f2bf(v);
}
__global__ void k_wsfail(float* out, int n, float v) {
  int i = blockIdx.x * 256 + threadIdx.x;
  if (i < n) out[i] = -v;
}

// ---------------- input projection ----------------
__global__ __launch_bounds__(256) void k_proj(const float* __restrict__ x,
                                              const unsigned short* __restrict__ WpT,
                                              const float* __restrict__ b_in,
                                              unsigned short* __restrict__ xin) {
  __shared__ short sA[4096], sB[4096];
  const int m0 = blockIdx.x * 64, n0 = blockIdx.y * 64;
  f32x4 acc[2][2];
  const f32x4 z = {0.f, 0.f, 0.f, 0.f};
  acc[0][0] = z; acc[0][1] = z; acc[1][0] = z; acc[1][1] = z;
  gemm_f32A<10, 300>(x + (size_t)m0 * 300, 300, WpT + n0 * 320, 320, sA, sB, acc);
  epiloop(acc, [&](int rowl, int coll, float vacc) {
    const int row = m0 + rowl, col = n0 + coll;
    float o = 0.0f;
    if (col < 300) o = tanh_(vacc + b_in[col]);
    const int b = row >> 8, s = row & 255;
    xin[(size_t)(s * 512 + b) * KP_ + col] = f2bf(o);
  });
}

// ---------------- persistent scan kernel ----------------
// 256 WGs x 512 threads (8 waves, 2/SIMD) in 8 independent groups of 32 WGs;
// group g owns batch rows 64g..64g+63. Dual-team K-split GEMM halves the
// serial K-chain (52 -> 26 rounds/step). Cross-WG data via sc0sc1 only.
// Barrier: single relaxed atomic counter per group (R6-proven).
__global__ __launch_bounds__(512, 2) void k_scan(
    const unsigned short* __restrict__ xin,
    const unsigned short* __restrict__ QpT,
    const unsigned short* __restrict__ RpT,
    const unsigned short* __restrict__ WgT,
    const float* __restrict__ bg,
    const unsigned short* __restrict__ VT,
    unsigned short* __restrict__ hs,
    unsigned short* __restrict__ act,
    float* __restrict__ hfp,
    float* __restrict__ U,
    unsigned int* __restrict__ bar)
{
  __shared__ short sA[8192], sB[8192];        // 2 round-bufs x 2 team slots x 4KB
  __shared__ float gbuf[4096];                // gates f32 / scratch
  __shared__ float rbuf[4096];                // team reduction / hfp-out staging
  __shared__ float pbuf[4096];                // P2 hfp preload
  __shared__ unsigned short obuf[4096];       // bf16 output tile staging
  const int wg   = blockIdx.x;
  const int grp  = wg >> 5;       // batch-row group: rows 64*grp .. 64*grp+63
  const int l    = wg & 31;       // lane-in-group
  const int tid  = threadIdx.x;
  const f32x4 z = {0.f, 0.f, 0.f, 0.f};

  // gates tile assignment (static across steps -> cell state in registers)
  const int gm0 = grp * 64;             // batch-row tile
  const int gn0 = l * 64;               // gate-col tile (permuted n' = 4c+g)
  float c_state[2] = {0.f, 0.f};        // 2 cells/thread (1024 items / 512 thr)

  int ep = 0;  // barrier epoch
  auto bar_sync = [&]() {
    wait_vm<0>();        // each wave drains its own system-stores to LLC
    __syncthreads();
    if (tid == 0) {
      __hip_atomic_fetch_add(&bar[grp * 64], 1u,
                             __ATOMIC_RELAXED, __HIP_MEMORY_SCOPE_AGENT);
      const unsigned tgt = (unsigned)(ep + 1) * 32u;
      while (__hip_atomic_load(&bar[grp * 64], __ATOMIC_RELAXED,
                               __HIP_MEMORY_SCOPE_AGENT) < tgt)
        __builtin_amdgcn_s_sleep(1);
    }
    __syncthreads();
    ++ep;
  };

  for (int t = 0; t < S_; ++t) {
    const unsigned short* hst = hs + (size_t)(t % NRING) * HSLOT;
    unsigned short*       hso = hs + (size_t)((t + 1) % NRING) * HSLOT;

    // ---- P1: act[g rows, 0:320] = 2*sigm(h_{t-1} @ Q) * xin_t  (5 tiles)
    if (l < 5) {
      const int m0 = gm0, n0 = l * 64;
      f32x4 acc[2][2];
      acc[0][0] = z; acc[0][1] = z; acc[1][0] = z; acc[1][1] = z;
      gemm2<8>(hst + m0 * 512, 512, QpT + n0 * 512, 512, sA, sB, acc);
      reduce_teams(acc, rbuf);
      if (tid < 256) {
        const unsigned short* xin_t = xin + (size_t)t * 512 * KP_;
        epiloop(acc, [&](int rowl, int coll, float vacc) {
          obuf[rowl * 64 + coll] =
            f2bf(2.0f * sigm(vacc) * bf2f(xin_t[(m0 + rowl) * KP_ + n0 + coll]));
        });
      }
      __syncthreads();
      pack_store_512(obuf, act + m0 * ALD_ + n0, ALD_);
    }
    bar_sync();

    // ---- P2: act[g rows, 320:832] = 2*sigm(xt @ R) * hfp  (8 tiles)
    if (l < 8) {
      const int m0 = gm0, n0 = l * 64;
      // cooperative hfp 64x64 tile preload: 2048 u64 over 512 threads
      {
        u64* p64 = (u64*)pbuf;
        #pragma unroll
        for (int it = 0; it < 4; ++it) {
          const int i = it * 512 + tid;
          const int row = i >> 5, p = i & 31;
          p64[row * 32 + p] = ld_sys_u64(hfp + (m0 + row) * 512 + n0 + p * 2);
        }
      }
      f32x4 acc[2][2];
      acc[0][0] = z; acc[0][1] = z; acc[1][0] = z; acc[1][1] = z;
      gemm2<5>(act + m0 * ALD_, ALD_, RpT + n0 * KP_, KP_, sA, sB, acc);
      reduce_teams(acc, rbuf);
      if (tid < 256) {
        epiloop(acc, [&](int rowl, int coll, float vacc) {
          obuf[rowl * 64 + coll] = f2bf(2.0f * sigm(vacc) * pbuf[rowl * 64 + coll]);
        });
      }
      __syncthreads();
      pack_store_512(obuf, act + m0 * ALD_ + 320 + n0, ALD_);
    }
    bar_sync();

    // ---- P3: gates GEMM + cell update (32 tiles, Ct in registers)
    {
      f32x4 acc[2][2];
      acc[0][0] = z; acc[0][1] = z; acc[1][0] = z; acc[1][1] = z;
      gemm2<13>(act + gm0 * ALD_, ALD_, WgT + gn0 * 832, 832, sA, sB, acc);
      reduce_teams(acc, rbuf);
      if (tid < 256) {
        epiloop(acc, [&](int rowl, int coll, float vacc) {
          gbuf[rowl * 64 + coll] = vacc;
        });
      }
      __syncthreads();
      unsigned short* hbuf = obuf;          // 64x16 u16
      float*          fbuf = rbuf;          // 64x16 f32 (reduction consumed)
      #pragma unroll
      for (int q = 0; q < 2; ++q) {
        const int item = q * 512 + tid;     // 1024 items = 64 rows x 16 cu
        const int row = item >> 4, cu = item & 15;
        const float4 bb = *(const float4*)&bg[gn0 + cu * 4];
        const float iv = gbuf[row * 64 + cu * 4 + 0] + bb.x;
        const float fv = gbuf[row * 64 + cu * 4 + 1] + bb.y;
        const float gv = gbuf[row * 64 + cu * 4 + 2] + bb.z;
        const float ov = gbuf[row * 64 + cu * 4 + 3] + bb.w;
        const float cn = sigm(fv) * c_state[q] + sigm(iv) * tanh_(gv);
        const float h  = sigm(ov) * tanh_(cn);
        c_state[q] = cn;
        hbuf[row * 16 + cu] = f2bf(h);
        fbuf[row * 16 + cu] = h;
      }
      __syncthreads();
      // pack-store h (256 u64) and hfp (512 u64)
      if (tid < 256) {
        const u64* h64 = (const u64*)hbuf;
        const int row = tid >> 2, q = tid & 3;
        st_sys_u64(hso + (gm0 + row) * 512 + (gn0 >> 2) + q * 4, h64[row * 4 + q]);
      }
      {
        const u64* f64 = (const u64*)fbuf;
        const int r2 = tid >> 3, p = tid & 7;
        st_sys_u64(hfp + (gm0 + r2) * 512 + (gn0 >> 2) + p * 2, f64[r2 * 8 + p]);
      }
    }
    bar_sync();

    // ---- convU every 32 steps: group handles its own 64 rows x 32 timesteps
    if ((t & 31) == 31) {
      const int c = t >> 5;
      const int tglob = 32 * c + l;
      const int slot = (tglob + 1) % NRING;
      const int brow = gm0;
      f32x4 acc[2][2];
      acc[0][0] = z; acc[0][1] = z; acc[1][0] = z; acc[1][1] = z;
      gemm2<8>(hs + (size_t)slot * HSLOT + (size_t)brow * 512, 512, VT, 512, sA, sB, acc);
      reduce_teams(acc, rbuf);
      if (tid < 256) {
        epiloop(acc, [&](int rowl, int coll, float vacc) {
          U[((size_t)(brow + rowl) * 256 + tglob) * 64 + coll] = vacc;
        });
      }
    }
  }
}

// window-sum + relu + global max pool + final linear
__global__ __launch_bounds__(256) void k_combine(const float* __restrict__ U,
                                                 const float* __restrict__ bc3,
                                                 const float* __restrict__ bc4,
                                                 const float* __restrict__ bc5,
                                                 const float* __restrict__ Wl,
                                                 const float* __restrict__ bl,
                                                 float* __restrict__ out) {
  const int b = blockIdx.x;
  const int p = threadIdx.x;
  const float* Ub = U + (size_t)b * (256 * 64);
  float v[9];
  #pragma unroll
  for (int j = 0; j < 9; ++j) v[j] = -1e30f;
  if (p < 254) {
    #pragma unroll
    for (int f = 0; f < 3; ++f)
      v[f] = Ub[(p + 0) * 64 + f * 3 + 0] + Ub[(p + 1) * 64 + f * 3 + 1] + Ub[(p + 2) * 64 + f * 3 + 2];
  }
  if (p < 253) {
    #pragma unroll
    for (int f = 0; f < 3; ++f)
      v[3 + f] = Ub[(p + 0) * 64 + 9 + f * 4 + 0] + Ub[(p + 1) * 64 + 9 + f * 4 + 1] +
                 Ub[(p + 2) * 64 + 9 + f * 4 + 2] + Ub[(p + 3) * 64 + 9 + f * 4 + 3];
  }
  if (p < 252) {
    #pragma unroll
    for (int f = 0; f < 3; ++f)
      v[6 + f] = Ub[(p + 0) * 64 + 21 + f * 5 + 0] + Ub[(p + 1) * 64 + 21 + f * 5 + 1] +
                 Ub[(p + 2) * 64 + 21 + f * 5 + 2] + Ub[(p + 3) * 64 + 21 + f * 5 + 3] +
                 Ub[(p + 4) * 64 + 21 + f * 5 + 4];
  }
  __shared__ float red[4][9];
  const int lane = threadIdx.x & 63, w = threadIdx.x >> 6;
  #pragma unroll
  for (int j = 0; j < 9; ++j) {
    float m = v[j];
    #pragma unroll
    for (int off = 32; off >= 1; off >>= 1) m = fmaxf(m, __shfl_xor(m, off));
    if (lane == 0) red[w][j] = m;
  }
  __syncthreads();
  if (threadIdx.x < 2) {
    const int k = threadIdx.x;
    float o = bl[k];
    #pragma unroll
    for (int j = 0; j < 9; ++j) {
      float m = fmaxf(fmaxf(red[0][j], red[1][j]), fmaxf(red[2][j], red[3][j]));
      float bias = (j < 3) ? bc3[j] : (j < 6) ? bc4[j - 3] : bc5[j - 6];
      o += fmaxf(m + bias, 0.0f) * Wl[j * 2 + k];
    }
    out[b * 2 + k] = o;
  }
}

// ---------------- host launch ----------------
extern "C" void kernel_launch(void* const* d_in, const int* in_sizes, int n_in,
                              void* d_out, int out_size, void* d_ws, size_t ws_size,
                              hipStream_t stream) {
  const float* x     = (const float*)d_in[0];
  const float* W_in  = (const float*)d_in[1];
  const float* b_in  = (const float*)d_in[2];
  const float* Wih   = (const float*)d_in[3];
  const float* Whh   = (const float*)d_in[4];
  const float* bih   = (const float*)d_in[5];
  const float* bhh   = (const float*)d_in[6];
  const float* Q     = (const float*)d_in[7];
  const float* R     = (const float*)d_in[8];
  const float* Wc3   = (const float*)d_in[9];
  const float* bc3   = (const float*)d_in[10];
  const float* Wc4   = (const float*)d_in[11];
  const float* bc4   = (const float*)d_in[12];
  const float* Wc5   = (const float*)d_in[13];
  const float* bc5   = (const float*)d_in[14];
  const float* W_lin = (const float*)d_in[15];
  const float* b_lin = (const float*)d_in[16];

  if (ws_size < WS_NEED) {  // diagnosable marker: absmax ≈ ws_size in MB
    k_wsfail<<<4, 256, 0, stream>>>((float*)d_out, out_size, (float)(ws_size >> 20));
    return;
  }

  char* ws = (char*)d_ws;
  unsigned short* xin = (unsigned short*)(ws + OFF_XIN);
  float*          U   = (float*)(ws + OFF_U);
  unsigned short* hs  = (unsigned short*)(ws + OFF_HS);
  unsigned short* act = (unsigned short*)(ws + OFF_ACT);
  float*          hfp = (float*)(ws + OFF_HFP);
  unsigned short* WpT = (unsigned short*)(ws + OFF_WPT);
  unsigned short* QpT = (unsigned short*)(ws + OFF_QPT);
  unsigned short* RpT = (unsigned short*)(ws + OFF_RPT);
  unsigned short* WgT = (unsigned short*)(ws + OFF_WGT);
  float*          bg  = (float*)(ws + OFF_BG);
  unsigned short* VT  = (unsigned short*)(ws + OFF_VT);
  unsigned int*   bar = (unsigned int*)(ws + OFF_BAR);

  // per-replay init: h0 = c0 = 0 (ring slot 0 + hfp), barrier counters = 0
  (void)hipMemsetAsync(hs, 0, HSLOT * 2, stream);
  (void)hipMemsetAsync(hfp, 0, SZ_HFP, stream);
  (void)hipMemsetAsync(bar, 0, SZ_BAR, stream);

  // weight prep
  k_prep_wpt<<<(320 * 320 + 255) / 256, 256, 0, stream>>>(W_in, WpT);
  k_prep_qpt<<<(320 * 512 + 255) / 256, 256, 0, stream>>>(Q, QpT);
  k_prep_rpt<<<(512 * 320 + 255) / 256, 256, 0, stream>>>(R, RpT);
  k_prep_wgt<<<(2048 * 832 + 255) / 256, 256, 0, stream>>>(Wih, Whh, WgT);
  k_prep_bg<<<8, 256, 0, stream>>>(bih, bhh, bg);
  k_prep_vt<<<(64 * 512 + 255) / 256, 256, 0, stream>>>(Wc3, Wc4, Wc5, VT);

  // input projection
  k_proj<<<dim3(131072 / 64, KP_ / 64), 256, 0, stream>>>(x, WpT, b_in, xin);

  // persistent scan (entire 256-step recurrence in one dispatch)
  k_scan<<<NWG, 512, 0, stream>>>(xin, QpT, RpT, WgT, bg, VT, hs, act, hfp, U, bar);

  // conv window-max + final linear
  k_combine<<<512, 256, 0, stream>>>(U, bc3, bc4, bc5, W_lin, b_lin, (float*)d_out);
}